// Round 2
// baseline (1678.251 us; speedup 1.0000x reference)
//
#include <hip/hip_runtime.h>
#include <cstddef>

typedef unsigned short u16;
typedef _Float16 f16x8 __attribute__((ext_vector_type(8)));
typedef float f32x4 __attribute__((ext_vector_type(4)));

#define NB  8
#define NW  5
#define NS  5
#define NC  640
#define NHW 100
#define NQ  75
#define ND  500   // S*hw descriptors
#define NDP 512   // padded cols
#define NR  7500  // Q*hw rows
#define NRP 7552  // padded rows = 59*128
#define NRT 59

// workspace byte offsets
#define OFF_SUP   ((size_t)0)           // u16 [NB][NW][NDP][NC]  26,214,400 B
#define OFF_ABF   ((size_t)26214400)    // u16 [NB][NRP][NC]      77,332,480 B
#define OFF_QRN   ((size_t)103546880)   // f32 [NB][NRP]             241,664 B
#define OFF_PROTO ((size_t)103788544)   // f32 [NB][NW][NC]          102,400 B

__device__ __forceinline__ u16 f2h_bits(float x) {
  _Float16 h = (_Float16)x;
  return __builtin_bit_cast(u16, h);
}
__device__ __forceinline__ float h2f_bits(u16 u) {
  return (float)__builtin_bit_cast(_Float16, u);
}

__device__ __forceinline__ float block_sum(float v, float* sc, int t) {
  v += __shfl_xor(v, 32, 64);
  v += __shfl_xor(v, 16, 64);
  v += __shfl_xor(v, 8, 64);
  v += __shfl_xor(v, 4, 64);
  v += __shfl_xor(v, 2, 64);
  v += __shfl_xor(v, 1, 64);
  __syncthreads();
  if ((t & 63) == 0) sc[t >> 6] = v;
  __syncthreads();
  return sc[0] + sc[1] + sc[2] + sc[3];
}

// k1: per (b,w,32-channel group). Single coalesced global pass through an LDS
// fp16 tile; per-channel descriptor-axis norms + raw proto sums from the tile.
__global__ __launch_bounds__(256) void k1_sup(const float* __restrict__ xs,
                                              u16* __restrict__ sup2,
                                              float* __restrict__ proto_g) {
  const int cc = blockIdx.x, w = blockIdx.y, b = blockIdx.z;
  const int t = threadIdx.x;
  __shared__ u16 tile[512 * 34];   // [d][c], stride 34 (17 words, odd -> spread)
  __shared__ float rn[32];
  const size_t bw = (size_t)b * NW + w;
  const float* xbase = xs + bw * NS * NC * NHW;   // [S][C][hw]
  const int cb = cc * 32;

  for (int s = 0; s < NS; s++) {
    const float4* rb = (const float4*)(xbase + ((size_t)s * NC + cb) * NHW);
    for (int i4 = t; i4 < 800; i4 += 256) {       // fully coalesced float4
      const float4 v = rb[i4];
      const int c = i4 / 25, p4 = i4 % 25;
      const int d = s * NHW + p4 * 4;
      tile[(d    ) * 34 + c] = f2h_bits(v.x);
      tile[(d + 1) * 34 + c] = f2h_bits(v.y);
      tile[(d + 2) * 34 + c] = f2h_bits(v.z);
      tile[(d + 3) * 34 + c] = f2h_bits(v.w);
    }
  }
  if (t < 384) tile[(500 + (t >> 5)) * 34 + (t & 31)] = 0;  // zero pad d 500..511
  __syncthreads();
  {
    const int c = t >> 3, part = t & 7;   // 32 c x 8 partials, from LDS
    float ss = 0.f, sm = 0.f;
    for (int d = part; d < ND; d += 8) {
      const float x = h2f_bits(tile[d * 34 + c]);
      ss += x * x; sm += x;
    }
    ss += __shfl_xor(ss, 1, 64); ss += __shfl_xor(ss, 2, 64); ss += __shfl_xor(ss, 4, 64);
    sm += __shfl_xor(sm, 1, 64); sm += __shfl_xor(sm, 2, 64); sm += __shfl_xor(sm, 4, 64);
    if (part == 0) {
      rn[c] = 1.0f / sqrtf(ss);
      proto_g[bw * NC + cb + c] = sm;     // raw sum; mean scales cancel in cosine
    }
  }
  __syncthreads();
  u16* obase = sup2 + bw * NDP * NC + cb;
  for (int idx = t; idx < 512 * 32; idx += 256) {
    const int cl = idx & 31, d = idx >> 5;
    obase[(size_t)d * NC + cl] = f2h_bits(h2f_bits(tile[d * 34 + cl]) * rn[cl]);
  }
}

// k2: per (b,q): coalesced transpose x_query -> Abf fp16 (unnormalized),
// qm/qs via explicit LDS reductions (no atomics), cosine branch -> out.
__global__ __launch_bounds__(256) void k2_query(const float* __restrict__ xq,
                                                const float* __restrict__ proto_g,
                                                const float* __restrict__ rcosp,
                                                u16* __restrict__ Abf,
                                                float* __restrict__ qrn,
                                                float* __restrict__ out) {
  const int q = blockIdx.x, b = blockIdx.y;
  const int t = threadIdx.x;
  __shared__ u16 tile[128 * 106];   // [c_local][p], stride 106 (53 words, odd)
  __shared__ float qm[NC];
  __shared__ float qs[NHW];
  __shared__ float sc[4];
  const float* xbase = xq + ((size_t)b * NQ + q) * NC * NHW;
  u16* abase = Abf + ((size_t)b * NRP + (size_t)q * NHW) * NC;

  if (t < NHW) qs[t] = 0.f;
  __syncthreads();

  for (int cc = 0; cc < 5; cc++) {          // 128-channel chunks
    const float4* rb = (const float4*)(xbase + (size_t)cc * 128 * NHW);
    for (int i4 = t; i4 < 3200; i4 += 256) {  // coalesced float4 reads
      const float4 xv = rb[i4];
      const int e = i4 * 4;
      const int p = e % NHW, cl = e / NHW;    // 4|100: never crosses a channel
      const unsigned lo = (unsigned)f2h_bits(xv.x) | ((unsigned)f2h_bits(xv.y) << 16);
      const unsigned hi = (unsigned)f2h_bits(xv.z) | ((unsigned)f2h_bits(xv.w) << 16);
      unsigned* tw = (unsigned*)&tile[cl * 106 + p];  // 8B-aligned (212*cl + 8*p4)
      tw[0] = lo; tw[1] = hi;
    }
    __syncthreads();
    if (t < 128) {                // qm: per-channel sum over p (dword reads)
      float s = 0.f;
      const unsigned* row = (const unsigned*)&tile[t * 106];
      for (int j = 0; j < 50; j++) {
        const unsigned u = row[j];
        s += h2f_bits((u16)(u & 0xffffu)) + h2f_bits((u16)(u >> 16));
      }
      qm[cc * 128 + t] = s;
    } else if (t < 228) {         // qs: per-p sumsq over this chunk's 128 c
      const int p = t - 128;
      float s = 0.f;
      for (int c = 0; c < 128; c++) {
        const float x = h2f_bits(tile[c * 106 + p]);
        s += x * x;
      }
      qs[p] += s;
    }
    {
      const int c0 = t & 63, pr = t >> 6;
      for (int p = pr; p < NHW; p += 4) {   // coalesced 128B fp16 writes
        abase[(size_t)p * NC + cc * 128 + c0]      = tile[c0 * 106 + p];
        abase[(size_t)p * NC + cc * 128 + c0 + 64] = tile[(c0 + 64) * 106 + p];
      }
    }
    __syncthreads();
  }
  if (t < NHW) qrn[(size_t)b * NRP + q * NHW + t] = 1.0f / sqrtf(qs[t]);

  // cosine: qn.pn = (qm.proto)/(|qm||proto|)
  float part = 0.f;
  for (int c = t; c < NC; c += 256) part += qm[c] * qm[c];
  const float qq = block_sum(part, sc, t);
  const float rcos = rcosp[0];
  for (int w = 0; w < NW; w++) {
    const float* pr_ = proto_g + ((size_t)b * NW + w) * NC;
    float dp = 0.f, pp = 0.f;
    for (int c = t; c < NC; c += 256) { const float pv = pr_[c]; dp += qm[c] * pv; pp += pv * pv; }
    dp = block_sum(dp, sc, t);
    pp = block_sum(pp, sc, t);
    if (t == 0) out[((size_t)b * NQ + q) * NW + w] = rcos * dp / sqrtf(qq * pp);
  }
  if (q == 0) {   // zero A pad rows [7500,7552) for this b
    u16* pz = Abf + ((size_t)b * NRP + NR) * NC;
    for (int i = t; i < (NRP - NR) * NC; i += 256) pz[i] = 0;
  }
}

// k4: per (b,w,128-row tile): 4 x [128x128x640 fp16 MFMA GEMM, BK=64
// register-prefetch pipeline -> LDS dump -> streaming top-5], scale+atomicAdd.
__global__ __launch_bounds__(256, 2) void k4_dn4(const u16* __restrict__ Abf,
                                                 const u16* __restrict__ sup2,
                                                 const float* __restrict__ qrn,
                                                 const float* __restrict__ rdn4p,
                                                 const int* __restrict__ nkp,
                                                 float* __restrict__ out) {
  const int rt = blockIdx.x, w = blockIdx.y, b = blockIdx.z;
  const int t = threadIdx.x;
  const int lane = t & 63, wid = t >> 6;
  const int m = lane & 15, quad = lane >> 4;
  const int wx = wid & 1, wy = wid >> 1;

  __shared__ __align__(16) char smem[36864];
  u16* lds_a = (u16*)smem;              // [128][72] fp16 (stride 144B: bank-uniform)
  u16* lds_b = (u16*)(smem + 18432);    // [128][72]
  u16* cd    = (u16*)smem;              // [128 cols][132 rows] fp16 dump (aliases)
  float* t5b = (float*)smem;            // [128][5] final merge (aliases)

  const u16* Ab = Abf + ((size_t)b * NRP + (size_t)rt * 128) * NC;
  const u16* Bb = sup2 + ((size_t)b * NW + w) * NDP * NC;

  const int rr = t >> 2;          // staging row 0..63
  const int c8 = (t & 3) * 8;     // k-offset within 32

  uint4 ra[4], rbv[4];            // in-flight K-slab (A/B, 2 row-halves x 2 k-halves)
  auto g_issue = [&](const u16* A0, const u16* B0, int k0) {
    const u16* ap = A0 + (size_t)rr * NC + k0 + c8;
    ra[0] = *(const uint4*)(ap);
    ra[1] = *(const uint4*)(ap + 32);
    ra[2] = *(const uint4*)(ap + (size_t)64 * NC);
    ra[3] = *(const uint4*)(ap + (size_t)64 * NC + 32);
    const u16* bp = B0 + (size_t)rr * NC + k0 + c8;
    rbv[0] = *(const uint4*)(bp);
    rbv[1] = *(const uint4*)(bp + 32);
    rbv[2] = *(const uint4*)(bp + (size_t)64 * NC);
    rbv[3] = *(const uint4*)(bp + (size_t)64 * NC + 32);
  };
  auto lds_store = [&]() {
    *(uint4*)&lds_a[rr * 72 + c8]             = ra[0];
    *(uint4*)&lds_a[rr * 72 + 32 + c8]        = ra[1];
    *(uint4*)&lds_a[(rr + 64) * 72 + c8]      = ra[2];
    *(uint4*)&lds_a[(rr + 64) * 72 + 32 + c8] = ra[3];
    *(uint4*)&lds_b[rr * 72 + c8]             = rbv[0];
    *(uint4*)&lds_b[rr * 72 + 32 + c8]        = rbv[1];
    *(uint4*)&lds_b[(rr + 64) * 72 + c8]      = rbv[2];
    *(uint4*)&lds_b[(rr + 64) * 72 + 32 + c8] = rbv[3];
  };

  float t5[5] = {-3e38f, -3e38f, -3e38f, -3e38f, -3e38f};  // sorted ascending
  const int half = t >> 7, rown = t & 127;

  g_issue(Ab, Bb, 0);   // prime ct=0, k0=0 (only cold-latency exposure)

  for (int ct = 0; ct < 4; ct++) {
    const u16* Bc = Bb + (size_t)ct * 128 * NC;
    f32x4 acc[4][4];
#pragma unroll
    for (int mt = 0; mt < 4; mt++)
#pragma unroll
      for (int nt = 0; nt < 4; nt++)
        acc[mt][nt] = (f32x4){0.f, 0.f, 0.f, 0.f};

    for (int k0 = 0; k0 < NC; k0 += 64) {
      __syncthreads();              // staging free (prev frag reads / scan done)
      lds_store();
      __syncthreads();              // slab visible
      if (k0 + 64 < NC) g_issue(Ab, Bc, k0 + 64);  // prefetch next slab; waited
                                                   // at next iter's lds_store
#pragma unroll
      for (int kh = 0; kh < 2; kh++) {
        f16x8 af[4], bfr[4];
#pragma unroll
        for (int mt = 0; mt < 4; mt++)
          af[mt] = *(const f16x8*)&lds_a[(wy * 64 + mt * 16 + m) * 72 + kh * 32 + quad * 8];
#pragma unroll
        for (int nt = 0; nt < 4; nt++)
          bfr[nt] = *(const f16x8*)&lds_b[(wx * 64 + nt * 16 + m) * 72 + kh * 32 + quad * 8];
#pragma unroll
        for (int mt = 0; mt < 4; mt++)
#pragma unroll
          for (int nt = 0; nt < 4; nt++)
            acc[mt][nt] = __builtin_amdgcn_mfma_f32_16x16x32_f16(af[mt], bfr[nt], acc[mt][nt], 0, 0, 0);
      }
    }
    __syncthreads();   // frag reads done; cd may alias staging
    // dump C col-major fp16: C/D layout col=lane&15, row=quad*4+reg
#pragma unroll
    for (int mt = 0; mt < 4; mt++)
#pragma unroll
      for (int nt = 0; nt < 4; nt++) {
        const int rb = wy * 64 + mt * 16 + quad * 4;
        const int cl = wx * 64 + nt * 16 + m;
        const unsigned lo = (unsigned)f2h_bits(acc[mt][nt].x) | ((unsigned)f2h_bits(acc[mt][nt].y) << 16);
        const unsigned hi = (unsigned)f2h_bits(acc[mt][nt].z) | ((unsigned)f2h_bits(acc[mt][nt].w) << 16);
        unsigned* dst = (unsigned*)&cd[cl * 132 + rb];
        dst[0] = lo; dst[1] = hi;
      }
    __syncthreads();
    if (ct < 3) g_issue(Ab, Bb + (size_t)(ct + 1) * 128 * NC, 0);  // hide behind scan
    // streaming top-5: 2 threads per row, 64 cols each; conflict-free scan
    const int dbase = ct * 128 + half * 64;
    for (int j = 0; j < 64; j++) {
      const int d = dbase + j;
      if (d >= ND) break;   // wave-uniform
      const float v = h2f_bits(cd[(half * 64 + j) * 132 + rown]);
      if (v > t5[0]) {
        t5[0] = v; float tmp;
        if (t5[0] > t5[1]) { tmp = t5[0]; t5[0] = t5[1]; t5[1] = tmp; }
        if (t5[1] > t5[2]) { tmp = t5[1]; t5[1] = t5[2]; t5[2] = tmp; }
        if (t5[2] > t5[3]) { tmp = t5[2]; t5[2] = t5[3]; t5[3] = tmp; }
        if (t5[3] > t5[4]) { tmp = t5[3]; t5[3] = t5[4]; t5[4] = tmp; }
      }
    }
  }
  __syncthreads();   // scan done; t5b may alias cd
  if (half == 1) {
#pragma unroll
    for (int i = 0; i < 5; i++) t5b[rown * 5 + i] = t5[i];
  }
  __syncthreads();
  if (half == 0) {
#pragma unroll
    for (int i = 0; i < 5; i++) {
      const float v = t5b[rown * 5 + i];
      if (v > t5[0]) {
        t5[0] = v; float tmp;
        if (t5[0] > t5[1]) { tmp = t5[0]; t5[0] = t5[1]; t5[1] = tmp; }
        if (t5[1] > t5[2]) { tmp = t5[1]; t5[1] = t5[2]; t5[2] = tmp; }
        if (t5[2] > t5[3]) { tmp = t5[2]; t5[2] = t5[3]; t5[3] = tmp; }
        if (t5[3] > t5[4]) { tmp = t5[3]; t5[3] = t5[4]; t5[4] = tmp; }
      }
    }
    const int r = rt * 128 + rown;
    if (r < NR) {
      const float s = t5[0] + t5[1] + t5[2] + t5[3] + t5[4];
      // fold per-row 1/|qd| (positive scale commutes with top-k), r_dn4, 1/k
      const float contrib = s * qrn[(size_t)b * NRP + r] * rdn4p[0] / (float)nkp[0];
      const int qi = r / NHW;
      atomicAdd(&out[((size_t)b * NQ + qi) * NW + w], contrib);
    }
  }
}

extern "C" void kernel_launch(void* const* d_in, const int* in_sizes, int n_in,
                              void* d_out, int out_size, void* d_ws, size_t ws_size,
                              hipStream_t stream) {
  (void)in_sizes; (void)n_in; (void)out_size; (void)ws_size;
  const float* xs   = (const float*)d_in[0];
  const float* xq   = (const float*)d_in[1];
  const float* rcos = (const float*)d_in[2];
  const float* rdn4 = (const float*)d_in[3];
  const int*   nk   = (const int*)d_in[4];
  float* out = (float*)d_out;
  char* ws = (char*)d_ws;
  u16*   sup2  = (u16*)(ws + OFF_SUP);
  u16*   Abf   = (u16*)(ws + OFF_ABF);
  float* qrn   = (float*)(ws + OFF_QRN);
  float* proto = (float*)(ws + OFF_PROTO);

  k1_sup <<<dim3(20, NW, NB),  dim3(256), 0, stream>>>(xs, sup2, proto);
  k2_query<<<dim3(NQ, NB),     dim3(256), 0, stream>>>(xq, proto, rcos, Abf, qrn, out);
  k4_dn4 <<<dim3(NRT, NW, NB), dim3(256), 0, stream>>>(Abf, sup2, qrn, rdn4, nk, out);
}

// Round 3
// 897.932 us; speedup vs baseline: 1.8690x; 1.8690x over previous
//
#include <hip/hip_runtime.h>
#include <cstddef>

typedef unsigned short u16;
typedef _Float16 f16x8 __attribute__((ext_vector_type(8)));
typedef float f32x4 __attribute__((ext_vector_type(4)));

#define NB  8
#define NW  5
#define NS  5
#define NC  640
#define NHW 100
#define NQ  75
#define ND  500   // S*hw descriptors
#define NDP 512   // padded cols
#define NR  7500  // Q*hw rows
#define NRP 7552  // padded rows = 59*128
#define NRT 59

// workspace byte offsets
#define OFF_SUP   ((size_t)0)           // u16 [NB][NW][NDP][NC]  26,214,400 B
#define OFF_ABF   ((size_t)26214400)    // u16 [NB][NRP][NC]      77,332,480 B
#define OFF_QRN   ((size_t)103546880)   // f32 [NB][NRP]             241,664 B
#define OFF_PROTO ((size_t)103788544)   // f32 [NB][NW][NC]          102,400 B

__device__ __forceinline__ u16 f2h_bits(float x) {
  _Float16 h = (_Float16)x;
  return __builtin_bit_cast(u16, h);
}
__device__ __forceinline__ float h2f_bits(u16 u) {
  return (float)__builtin_bit_cast(_Float16, u);
}

__device__ __forceinline__ float block_sum(float v, float* sc, int t) {
  v += __shfl_xor(v, 32, 64);
  v += __shfl_xor(v, 16, 64);
  v += __shfl_xor(v, 8, 64);
  v += __shfl_xor(v, 4, 64);
  v += __shfl_xor(v, 2, 64);
  v += __shfl_xor(v, 1, 64);
  __syncthreads();
  if ((t & 63) == 0) sc[t >> 6] = v;
  __syncthreads();
  return sc[0] + sc[1] + sc[2] + sc[3];
}

// k1: per (b,w,32-channel group). Single coalesced global pass through an LDS
// fp16 tile; per-channel descriptor-axis norms + raw proto sums from the tile.
__global__ __launch_bounds__(256) void k1_sup(const float* __restrict__ xs,
                                              u16* __restrict__ sup2,
                                              float* __restrict__ proto_g) {
  const int cc = blockIdx.x, w = blockIdx.y, b = blockIdx.z;
  const int t = threadIdx.x;
  __shared__ u16 tile[512 * 34];   // [d][c], stride 34 (17 words, odd -> spread)
  __shared__ float rn[32];
  const size_t bw = (size_t)b * NW + w;
  const float* xbase = xs + bw * NS * NC * NHW;   // [S][C][hw]
  const int cb = cc * 32;

  for (int s = 0; s < NS; s++) {
    const float4* rb = (const float4*)(xbase + ((size_t)s * NC + cb) * NHW);
    for (int i4 = t; i4 < 800; i4 += 256) {       // fully coalesced float4
      const float4 v = rb[i4];
      const int c = i4 / 25, p4 = i4 % 25;
      const int d = s * NHW + p4 * 4;
      tile[(d    ) * 34 + c] = f2h_bits(v.x);
      tile[(d + 1) * 34 + c] = f2h_bits(v.y);
      tile[(d + 2) * 34 + c] = f2h_bits(v.z);
      tile[(d + 3) * 34 + c] = f2h_bits(v.w);
    }
  }
  if (t < 384) tile[(500 + (t >> 5)) * 34 + (t & 31)] = 0;  // zero pad d 500..511
  __syncthreads();
  {
    const int c = t >> 3, part = t & 7;   // 32 c x 8 partials, from LDS
    float ss = 0.f, sm = 0.f;
    for (int d = part; d < ND; d += 8) {
      const float x = h2f_bits(tile[d * 34 + c]);
      ss += x * x; sm += x;
    }
    ss += __shfl_xor(ss, 1, 64); ss += __shfl_xor(ss, 2, 64); ss += __shfl_xor(ss, 4, 64);
    sm += __shfl_xor(sm, 1, 64); sm += __shfl_xor(sm, 2, 64); sm += __shfl_xor(sm, 4, 64);
    if (part == 0) {
      rn[c] = 1.0f / sqrtf(ss);
      proto_g[bw * NC + cb + c] = sm;     // raw sum; mean scales cancel in cosine
    }
  }
  __syncthreads();
  u16* obase = sup2 + bw * NDP * NC + cb;
  for (int idx = t; idx < 512 * 32; idx += 256) {
    const int cl = idx & 31, d = idx >> 5;
    obase[(size_t)d * NC + cl] = f2h_bits(h2f_bits(tile[d * 34 + cl]) * rn[cl]);
  }
}

// k2: per (b,q): coalesced transpose x_query -> Abf fp16 (unnormalized),
// qm/qs via explicit LDS reductions (no atomics), cosine branch -> out.
__global__ __launch_bounds__(256) void k2_query(const float* __restrict__ xq,
                                                const float* __restrict__ proto_g,
                                                const float* __restrict__ rcosp,
                                                u16* __restrict__ Abf,
                                                float* __restrict__ qrn,
                                                float* __restrict__ out) {
  const int q = blockIdx.x, b = blockIdx.y;
  const int t = threadIdx.x;
  __shared__ u16 tile[128 * 106];   // [c_local][p], stride 106 (53 words, odd)
  __shared__ float qm[NC];
  __shared__ float qs[NHW];
  __shared__ float sc[4];
  const float* xbase = xq + ((size_t)b * NQ + q) * NC * NHW;
  u16* abase = Abf + ((size_t)b * NRP + (size_t)q * NHW) * NC;

  if (t < NHW) qs[t] = 0.f;
  __syncthreads();

  for (int cc = 0; cc < 5; cc++) {          // 128-channel chunks
    const float4* rb = (const float4*)(xbase + (size_t)cc * 128 * NHW);
    for (int i4 = t; i4 < 3200; i4 += 256) {  // coalesced float4 reads
      const float4 xv = rb[i4];
      const int e = i4 * 4;
      const int p = e % NHW, cl = e / NHW;    // 4|100: never crosses a channel
      const unsigned lo = (unsigned)f2h_bits(xv.x) | ((unsigned)f2h_bits(xv.y) << 16);
      const unsigned hi = (unsigned)f2h_bits(xv.z) | ((unsigned)f2h_bits(xv.w) << 16);
      unsigned* tw = (unsigned*)&tile[cl * 106 + p];  // 8B-aligned (212*cl + 8*p4)
      tw[0] = lo; tw[1] = hi;
    }
    __syncthreads();
    if (t < 128) {                // qm: per-channel sum over p (dword reads)
      float s = 0.f;
      const unsigned* row = (const unsigned*)&tile[t * 106];
      for (int j = 0; j < 50; j++) {
        const unsigned u = row[j];
        s += h2f_bits((u16)(u & 0xffffu)) + h2f_bits((u16)(u >> 16));
      }
      qm[cc * 128 + t] = s;
    } else if (t < 228) {         // qs: per-p sumsq over this chunk's 128 c
      const int p = t - 128;
      float s = 0.f;
      for (int c = 0; c < 128; c++) {
        const float x = h2f_bits(tile[c * 106 + p]);
        s += x * x;
      }
      qs[p] += s;
    }
    {
      const int c0 = t & 63, pr = t >> 6;
      for (int p = pr; p < NHW; p += 4) {   // coalesced 128B fp16 writes
        abase[(size_t)p * NC + cc * 128 + c0]      = tile[c0 * 106 + p];
        abase[(size_t)p * NC + cc * 128 + c0 + 64] = tile[(c0 + 64) * 106 + p];
      }
    }
    __syncthreads();
  }
  if (t < NHW) qrn[(size_t)b * NRP + q * NHW + t] = 1.0f / sqrtf(qs[t]);

  // cosine: qn.pn = (qm.proto)/(|qm||proto|)
  float part = 0.f;
  for (int c = t; c < NC; c += 256) part += qm[c] * qm[c];
  const float qq = block_sum(part, sc, t);
  const float rcos = rcosp[0];
  for (int w = 0; w < NW; w++) {
    const float* pr_ = proto_g + ((size_t)b * NW + w) * NC;
    float dp = 0.f, pp = 0.f;
    for (int c = t; c < NC; c += 256) { const float pv = pr_[c]; dp += qm[c] * pv; pp += pv * pv; }
    dp = block_sum(dp, sc, t);
    pp = block_sum(pp, sc, t);
    if (t == 0) out[((size_t)b * NQ + q) * NW + w] = rcos * dp / sqrtf(qq * pp);
  }
  if (q == 0) {   // zero A pad rows [7500,7552) for this b
    u16* pz = Abf + ((size_t)b * NRP + NR) * NC;
    for (int i = t; i < (NRP - NR) * NC; i += 256) pz[i] = 0;
  }
}

// k4: per (b,w,128-row tile). Flat 80-slab (BK=32) double-buffered LDS
// ping-pong with register prefetch (NO lambdas/arrays -> no scratch).
// Per ct chunk of 128 cols: accumulate 128x128x640, dump fp16 col-major to cd,
// streaming top-5; epilogue scale+atomicAdd.
__global__ __launch_bounds__(256, 2) void k4_dn4(const u16* __restrict__ Abf,
                                                 const u16* __restrict__ sup2,
                                                 const float* __restrict__ qrn,
                                                 const float* __restrict__ rdn4p,
                                                 const int* __restrict__ nkp,
                                                 float* __restrict__ out) {
  const int rt = blockIdx.x, w = blockIdx.y, b = blockIdx.z;
  const int t = threadIdx.x;
  const int lane = t & 63, wid = t >> 6;
  const int m = lane & 15, quad = lane >> 4;
  const int wx = wid & 1, wy = wid >> 1;

  __shared__ __align__(16) u16 stg[2][2][128 * 40];  // [buf][a|b][row][k] 40960 B
  __shared__ __align__(16) u16 cd[128 * 132];        // [col][row-padded] 33792 B
  float* t5b = (float*)cd;                           // [128][5] merge (aliases cd)

  const u16* Ab = Abf + ((size_t)b * NRP + (size_t)rt * 128) * NC;
  const u16* Bb = sup2 + ((size_t)b * NW + w) * NDP * NC;

  const int rr = t >> 2;          // staging row 0..63
  const int c8 = (t & 3) * 8;     // k-offset within slab

  uint4 ra0, ra1, rb0, rb1;       // in-flight slab (plain scalars: stay in VGPRs)

#define G_LOAD2(CT_, K0_) do {                                            \
    const u16* ap_ = Ab + (size_t)rr * NC + (K0_) + c8;                   \
    ra0 = *(const uint4*)ap_;                                             \
    ra1 = *(const uint4*)(ap_ + (size_t)64 * NC);                         \
    const u16* bp_ = Bb + (size_t)((CT_) * 128 + rr) * NC + (K0_) + c8;   \
    rb0 = *(const uint4*)bp_;                                             \
    rb1 = *(const uint4*)(bp_ + (size_t)64 * NC);                         \
  } while (0)

#define LDS_STORE(BUF_) do {                                              \
    *(uint4*)&stg[BUF_][0][rr * 40 + c8]        = ra0;                    \
    *(uint4*)&stg[BUF_][0][(rr + 64) * 40 + c8] = ra1;                    \
    *(uint4*)&stg[BUF_][1][rr * 40 + c8]        = rb0;                    \
    *(uint4*)&stg[BUF_][1][(rr + 64) * 40 + c8] = rb1;                    \
  } while (0)

  float t5[5] = {-3e38f, -3e38f, -3e38f, -3e38f, -3e38f};  // sorted ascending
  const int half = t >> 7, rown = t & 127;

  // ---- pipeline prologue: slab0 -> buf0, slab1 in regs ----
  G_LOAD2(0, 0);
  LDS_STORE(0);
  G_LOAD2(0, 32);
  __syncthreads();

  for (int ct = 0; ct < 4; ct++) {
    f32x4 acc[4][4];
#pragma unroll
    for (int mt = 0; mt < 4; mt++)
#pragma unroll
      for (int nt = 0; nt < 4; nt++)
        acc[mt][nt] = (f32x4){0.f, 0.f, 0.f, 0.f};

    for (int s = 0; s < 20; s++) {
      // regs hold slab g+1 (g = ct*20+s): store into the other buffer
      if (!(ct == 3 && s == 19)) LDS_STORE((s + 1) & 1);
      // issue global loads for slab g+2; vmcnt waited at NEXT iter's store
      if (!(ct == 3 && s >= 18)) {
        const int ctn = (s < 18) ? ct : ct + 1;
        const int k0n = ((s < 18) ? (s + 2) : (s - 18)) * 32;
        G_LOAD2(ctn, k0n);
      }
      // compute from buf s&1 (slab g)
      {
        const u16* la = &stg[s & 1][0][0];
        const u16* lb = &stg[s & 1][1][0];
        f16x8 af0, af1, af2, af3, bf0, bf1, bf2, bf3;
        af0 = *(const f16x8*)&la[(wy * 64 +  0 + m) * 40 + quad * 8];
        af1 = *(const f16x8*)&la[(wy * 64 + 16 + m) * 40 + quad * 8];
        af2 = *(const f16x8*)&la[(wy * 64 + 32 + m) * 40 + quad * 8];
        af3 = *(const f16x8*)&la[(wy * 64 + 48 + m) * 40 + quad * 8];
        bf0 = *(const f16x8*)&lb[(wx * 64 +  0 + m) * 40 + quad * 8];
        bf1 = *(const f16x8*)&lb[(wx * 64 + 16 + m) * 40 + quad * 8];
        bf2 = *(const f16x8*)&lb[(wx * 64 + 32 + m) * 40 + quad * 8];
        bf3 = *(const f16x8*)&lb[(wx * 64 + 48 + m) * 40 + quad * 8];
        acc[0][0] = __builtin_amdgcn_mfma_f32_16x16x32_f16(af0, bf0, acc[0][0], 0, 0, 0);
        acc[0][1] = __builtin_amdgcn_mfma_f32_16x16x32_f16(af0, bf1, acc[0][1], 0, 0, 0);
        acc[0][2] = __builtin_amdgcn_mfma_f32_16x16x32_f16(af0, bf2, acc[0][2], 0, 0, 0);
        acc[0][3] = __builtin_amdgcn_mfma_f32_16x16x32_f16(af0, bf3, acc[0][3], 0, 0, 0);
        acc[1][0] = __builtin_amdgcn_mfma_f32_16x16x32_f16(af1, bf0, acc[1][0], 0, 0, 0);
        acc[1][1] = __builtin_amdgcn_mfma_f32_16x16x32_f16(af1, bf1, acc[1][1], 0, 0, 0);
        acc[1][2] = __builtin_amdgcn_mfma_f32_16x16x32_f16(af1, bf2, acc[1][2], 0, 0, 0);
        acc[1][3] = __builtin_amdgcn_mfma_f32_16x16x32_f16(af1, bf3, acc[1][3], 0, 0, 0);
        acc[2][0] = __builtin_amdgcn_mfma_f32_16x16x32_f16(af2, bf0, acc[2][0], 0, 0, 0);
        acc[2][1] = __builtin_amdgcn_mfma_f32_16x16x32_f16(af2, bf1, acc[2][1], 0, 0, 0);
        acc[2][2] = __builtin_amdgcn_mfma_f32_16x16x32_f16(af2, bf2, acc[2][2], 0, 0, 0);
        acc[2][3] = __builtin_amdgcn_mfma_f32_16x16x32_f16(af2, bf3, acc[2][3], 0, 0, 0);
        acc[3][0] = __builtin_amdgcn_mfma_f32_16x16x32_f16(af3, bf0, acc[3][0], 0, 0, 0);
        acc[3][1] = __builtin_amdgcn_mfma_f32_16x16x32_f16(af3, bf1, acc[3][1], 0, 0, 0);
        acc[3][2] = __builtin_amdgcn_mfma_f32_16x16x32_f16(af3, bf2, acc[3][2], 0, 0, 0);
        acc[3][3] = __builtin_amdgcn_mfma_f32_16x16x32_f16(af3, bf3, acc[3][3], 0, 0, 0);
      }
      __syncthreads();   // compute(buf s&1) done everywhere; stores of slab g+1 visible
    }

    // dump C col-major fp16: C/D layout col=lane&15, row=quad*4+reg
#pragma unroll
    for (int mt = 0; mt < 4; mt++)
#pragma unroll
      for (int nt = 0; nt < 4; nt++) {
        const int rb_ = wy * 64 + mt * 16 + quad * 4;
        const int cl = wx * 64 + nt * 16 + m;
        const unsigned lo = (unsigned)f2h_bits(acc[mt][nt].x) | ((unsigned)f2h_bits(acc[mt][nt].y) << 16);
        const unsigned hi = (unsigned)f2h_bits(acc[mt][nt].z) | ((unsigned)f2h_bits(acc[mt][nt].w) << 16);
        unsigned* dst = (unsigned*)&cd[cl * 132 + rb_];
        dst[0] = lo; dst[1] = hi;
      }
    __syncthreads();
    // streaming top-5: 2 threads per row, 64 cols each
    const int dbase = ct * 128 + half * 64;
    for (int j = 0; j < 64; j++) {
      const int d = dbase + j;
      if (d >= ND) break;   // wave-uniform (skip zero pad cols 500..511)
      const float v = h2f_bits(cd[(half * 64 + j) * 132 + rown]);
      if (v > t5[0]) {
        t5[0] = v; float tmp;
        if (t5[0] > t5[1]) { tmp = t5[0]; t5[0] = t5[1]; t5[1] = tmp; }
        if (t5[1] > t5[2]) { tmp = t5[1]; t5[1] = t5[2]; t5[2] = tmp; }
        if (t5[2] > t5[3]) { tmp = t5[2]; t5[2] = t5[3]; t5[3] = tmp; }
        if (t5[3] > t5[4]) { tmp = t5[3]; t5[3] = t5[4]; t5[4] = tmp; }
      }
    }
    __syncthreads();   // scan done before next ct's dump overwrites cd
  }

  // merge the two halves' top-5 via LDS, then reduce + write
  if (half == 1) {
#pragma unroll
    for (int i = 0; i < 5; i++) t5b[rown * 5 + i] = t5[i];
  }
  __syncthreads();
  if (half == 0) {
#pragma unroll
    for (int i = 0; i < 5; i++) {
      const float v = t5b[rown * 5 + i];
      if (v > t5[0]) {
        t5[0] = v; float tmp;
        if (t5[0] > t5[1]) { tmp = t5[0]; t5[0] = t5[1]; t5[1] = tmp; }
        if (t5[1] > t5[2]) { tmp = t5[1]; t5[1] = t5[2]; t5[2] = tmp; }
        if (t5[2] > t5[3]) { tmp = t5[2]; t5[2] = t5[3]; t5[3] = tmp; }
        if (t5[3] > t5[4]) { tmp = t5[3]; t5[3] = t5[4]; t5[4] = tmp; }
      }
    }
    const int r = rt * 128 + rown;
    if (r < NR) {
      const float s = t5[0] + t5[1] + t5[2] + t5[3] + t5[4];
      // fold per-row 1/|qd| (positive scale commutes with top-k), r_dn4, 1/k
      const float contrib = s * qrn[(size_t)b * NRP + r] * rdn4p[0] / (float)nkp[0];
      const int qi = r / NHW;
      atomicAdd(&out[((size_t)b * NQ + qi) * NW + w], contrib);
    }
  }
#undef G_LOAD2
#undef LDS_STORE
}

extern "C" void kernel_launch(void* const* d_in, const int* in_sizes, int n_in,
                              void* d_out, int out_size, void* d_ws, size_t ws_size,
                              hipStream_t stream) {
  (void)in_sizes; (void)n_in; (void)out_size; (void)ws_size;
  const float* xs   = (const float*)d_in[0];
  const float* xq   = (const float*)d_in[1];
  const float* rcos = (const float*)d_in[2];
  const float* rdn4 = (const float*)d_in[3];
  const int*   nk   = (const int*)d_in[4];
  float* out = (float*)d_out;
  char* ws = (char*)d_ws;
  u16*   sup2  = (u16*)(ws + OFF_SUP);
  u16*   Abf   = (u16*)(ws + OFF_ABF);
  float* qrn   = (float*)(ws + OFF_QRN);
  float* proto = (float*)(ws + OFF_PROTO);

  k1_sup <<<dim3(20, NW, NB),  dim3(256), 0, stream>>>(xs, sup2, proto);
  k2_query<<<dim3(NQ, NB),     dim3(256), 0, stream>>>(xq, proto, rcos, Abf, qrn, out);
  k4_dn4 <<<dim3(NRT, NW, NB), dim3(256), 0, stream>>>(Abf, sup2, qrn, rdn4, nk, out);
}